// Round 1
// baseline (105.986 us; speedup 1.0000x reference)
//
#include <hip/hip_runtime.h>

// Problem constants (fixed by setup_inputs): B=4, T=28, N=1024, D=3
constexpr int Bc = 4;
constexpr int Tc = 28;
constexpr int Nc = 1024;
constexpr int Dc = 3;
constexpr int BT = Bc * Tc;              // 112
constexpr int BLOCKS_PER_BT = 4;         // 4 chunks of 256 pred points
constexpr int CHUNK = Nc / BLOCKS_PER_BT; // 256

__device__ __forceinline__ float smooth_l1_1(float diff) {
    float d = fabsf(diff);
    return d < 1.0f ? 0.5f * d * d : d - 0.5f;
}

// One block = one chunk of 256 pred points for one (b,t).
// Targets for the (b,t) staged in LDS (12 KB); inner loop is wave-uniform
// LDS reads (broadcast, conflict-free) + ~9 VALU ops per distance eval.
__global__ __launch_bounds__(256) void chamfer_kernel(
    const float* __restrict__ X, const float* __restrict__ Tg,
    const float* __restrict__ W, float* __restrict__ out)
{
    __shared__ float sT[Nc * Dc];  // 3072 floats = 12 KB
    __shared__ float sred[4];

    const int bt    = blockIdx.x / BLOCKS_PER_BT;
    const int chunk = blockIdx.x % BLOCKS_PER_BT;
    const int tid   = threadIdx.x;

    const float* __restrict__ tgt = Tg + (size_t)bt * (Nc * Dc);
    const float* __restrict__ xp  = X  + (size_t)bt * (Nc * Dc);

    // Stage targets: 3072 floats = 768 float4; (b,t) base offset is
    // 12288 B -> 16 B aligned, so float4 loads are legal.
    const float4* tgt4 = (const float4*)tgt;
    float4* sT4 = (float4*)sT;
    #pragma unroll
    for (int i = 0; i < (Nc * Dc / 4) / 256; ++i)   // 3 iterations
        sT4[tid + i * 256] = tgt4[tid + i * 256];
    __syncthreads();

    const int n = chunk * CHUNK + tid;
    const float px = xp[n * 3 + 0];
    const float py = xp[n * 3 + 1];
    const float pz = xp[n * 3 + 2];

    float best = 3.4e38f;
    int bidx = 0;
    #pragma unroll 4
    for (int m = 0; m < Nc; ++m) {
        float dx = px - sT[m * 3 + 0];
        float dy = py - sT[m * 3 + 1];
        float dz = pz - sT[m * 3 + 2];
        float d = dx * dx + dy * dy + dz * dz;
        // strict < keeps the FIRST minimum -> matches jnp.argmin tie-break
        bool c = d < best;
        best = c ? d : best;
        bidx = c ? m : bidx;
    }

    const float tx = sT[bidx * 3 + 0];
    const float ty = sT[bidx * 3 + 1];
    const float tz = sT[bidx * 3 + 2];
    float s = smooth_l1_1(px - tx) + smooth_l1_1(py - ty) + smooth_l1_1(pz - tz);

    // block reduction: wave shuffle then cross-wave via LDS
    #pragma unroll
    for (int off = 32; off > 0; off >>= 1) s += __shfl_down(s, off, 64);
    const int lane = tid & 63, wid = tid >> 6;
    if (lane == 0) sred[wid] = s;
    __syncthreads();
    if (tid == 0) {
        float tot = sred[0] + sred[1] + sred[2] + sred[3];
        // loss_bt = sum / (N*D); loss = sum_bt loss_bt * w_bt / B
        atomicAdd(out, tot * W[bt] * (1.0f / (Nc * Dc)) * (1.0f / Bc));
    }
}

// Centroid loss: needs per-(b,t) means BEFORE the nonlinearity, so it is a
// separate tiny kernel (112 blocks). Cost ~ reading 2.75 MB from L2.
__global__ __launch_bounds__(256) void centroid_kernel(
    const float* __restrict__ X, const float* __restrict__ Tg,
    float* __restrict__ out)
{
    const int bt = blockIdx.x;
    const int tid = threadIdx.x;
    const float* __restrict__ xp = X  + (size_t)bt * (Nc * Dc);
    const float* __restrict__ tp = Tg + (size_t)bt * (Nc * Dc);

    float v[6] = {0.f, 0.f, 0.f, 0.f, 0.f, 0.f};
    for (int i = tid; i < Nc; i += 256) {
        v[0] += xp[i * 3 + 0]; v[1] += xp[i * 3 + 1]; v[2] += xp[i * 3 + 2];
        v[3] += tp[i * 3 + 0]; v[4] += tp[i * 3 + 1]; v[5] += tp[i * 3 + 2];
    }

    __shared__ float sbuf[4][6];
    const int lane = tid & 63, wid = tid >> 6;
    #pragma unroll
    for (int k = 0; k < 6; ++k) {
        float x = v[k];
        #pragma unroll
        for (int off = 32; off > 0; off >>= 1) x += __shfl_down(x, off, 64);
        if (lane == 0) sbuf[wid][k] = x;
    }
    __syncthreads();
    if (tid == 0) {
        float s = 0.f;
        #pragma unroll
        for (int c = 0; c < 3; ++c) {
            float pm = (sbuf[0][c]     + sbuf[1][c]     + sbuf[2][c]     + sbuf[3][c])     * (1.0f / Nc);
            float tm = (sbuf[0][c + 3] + sbuf[1][c + 3] + sbuf[2][c + 3] + sbuf[3][c + 3]) * (1.0f / Nc);
            s += smooth_l1_1(pm - tm);
        }
        // lossc = sum over [B,T,3] / (B*3)
        atomicAdd(out + 1, s * (1.0f / (Bc * Dc)));
    }
}

extern "C" void kernel_launch(void* const* d_in, const int* in_sizes, int n_in,
                              void* d_out, int out_size, void* d_ws, size_t ws_size,
                              hipStream_t stream) {
    const float* X  = (const float*)d_in[0];  // X_v        [4,28,1024,3]
    const float* Tg = (const float*)d_in[1];  // target_X_v [4,28,1024,3]
    const float* W  = (const float*)d_in[2];  // weights    [4,28]
    float* out = (float*)d_out;               // {loss, lossc}

    // d_out is poisoned to 0xAA before every timed launch — zero it.
    hipMemsetAsync(out, 0, 2 * sizeof(float), stream);

    chamfer_kernel<<<BT * BLOCKS_PER_BT, 256, 0, stream>>>(X, Tg, W, out);
    centroid_kernel<<<BT, 256, 0, stream>>>(X, Tg, out);
}

// Round 2
// 100.144 us; speedup vs baseline: 1.0583x; 1.0583x over previous
//
#include <hip/hip_runtime.h>

// Problem constants (fixed by setup_inputs): B=4, T=28, N=1024, D=3
constexpr int Bc = 4;
constexpr int Tc = 28;
constexpr int Nc = 1024;
constexpr int Dc = 3;
constexpr int BT = Bc * Tc;     // 112
constexpr int HALF = 512;       // target-half and pred-half size
constexpr float OFFS = 512.0f;  // keeps surrogate distance positive -> fp32 bits order-preserving

__device__ __forceinline__ float sl1(float d) {
    d = fabsf(d);
    return d < 1.0f ? 0.5f * d * d : d - 0.5f;
}

__device__ __forceinline__ float blockSum(float v, int tid, float* scratch) {
    #pragma unroll
    for (int off = 32; off; off >>= 1) v += __shfl_down(v, off, 64);
    if ((tid & 63) == 0) scratch[tid >> 6] = v;
    __syncthreads();
    float r = scratch[0] + scratch[1] + scratch[2] + scratch[3];
    __syncthreads();
    return r;
}

// Grid: 448 = 112 (b,t) x 2 pred-halves x 2 target-halves. Block: 256.
// Each thread owns 2 preds; inner loop: 1 ds_read_b128 (broadcast) + 12 VALU
// for 2 distance-surrogate evals: v = (||t||^2+512) - 2 p.t  (argmin-equivalent).
// Cross-target-half combine via atomicMin on key = (fp32bits(v)<<32 | idx):
// min picks smallest v, tie -> smallest idx == jnp.argmin first-occurrence.
__global__ __launch_bounds__(256) void chamfer_part_kernel(
    const float* __restrict__ X, const float* __restrict__ Tg,
    unsigned long long* __restrict__ keys, float* __restrict__ cent)
{
    __shared__ float sRaw[HALF * 3];   // 6 KB staging
    __shared__ float4 sT4[HALF];       // 8 KB packed [x,y,z,||t||^2+512]
    __shared__ float sred[4];

    const int bt  = blockIdx.x >> 2;
    const int ph  = (blockIdx.x >> 1) & 1;  // pred half
    const int th  = blockIdx.x & 1;         // target half
    const int tid = threadIdx.x;

    // ---- stage + pack this (b,t)'s target half ----
    const float* tg = Tg + (size_t)bt * (Nc * Dc) + th * (HALF * 3);
    const float4* tg4 = (const float4*)tg;   // 6144-byte offsets -> 16B aligned
    float4* sR4 = (float4*)sRaw;
    #pragma unroll
    for (int i = 0; i < (HALF * 3 / 4) / 256 + 1; ++i) {
        int j = tid + i * 256;
        if (j < HALF * 3 / 4) sR4[j] = tg4[j];
    }
    __syncthreads();

    float x0 = sRaw[6 * tid + 0], y0 = sRaw[6 * tid + 1], z0 = sRaw[6 * tid + 2];
    float x1 = sRaw[6 * tid + 3], y1 = sRaw[6 * tid + 4], z1 = sRaw[6 * tid + 5];
    sT4[2 * tid]     = make_float4(x0, y0, z0, fmaf(x0, x0, fmaf(y0, y0, fmaf(z0, z0, OFFS))));
    sT4[2 * tid + 1] = make_float4(x1, y1, z1, fmaf(x1, x1, fmaf(y1, y1, fmaf(z1, z1, OFFS))));
    __syncthreads();

    // ---- load 2 preds per thread ----
    const float* xb = X + (size_t)bt * (Nc * Dc);
    const int n0 = ph * HALF + tid;
    const int n1 = n0 + 256;
    const float pAx = xb[n0 * 3 + 0], pAy = xb[n0 * 3 + 1], pAz = xb[n0 * 3 + 2];
    const float pBx = xb[n1 * 3 + 0], pBy = xb[n1 * 3 + 1], pBz = xb[n1 * 3 + 2];
    const float cA0 = -2.0f * pAx, cA1 = -2.0f * pAy, cA2 = -2.0f * pAz;
    const float cB0 = -2.0f * pBx, cB1 = -2.0f * pBy, cB2 = -2.0f * pBz;

    float bestA = 3.4e38f, bestB = 3.4e38f;
    int iA = 0, iB = 0;
    #pragma unroll 4
    for (int m = 0; m < HALF; ++m) {
        const float4 t = sT4[m];  // broadcast b128: conflict-free, 1 LDS issue
        float vA = fmaf(cA0, t.x, fmaf(cA1, t.y, fmaf(cA2, t.z, t.w)));
        float vB = fmaf(cB0, t.x, fmaf(cB1, t.y, fmaf(cB2, t.z, t.w)));
        bool ca = vA < bestA; bestA = ca ? vA : bestA; iA = ca ? m : iA;  // strict <: first min
        bool cb = vB < bestB; bestB = cb ? vB : bestB; iB = cb ? m : iB;
    }

    const unsigned mbase = th * HALF;
    unsigned long long kA =
        ((unsigned long long)__float_as_uint(bestA) << 32) | (unsigned long long)((unsigned)iA + mbase);
    unsigned long long kB =
        ((unsigned long long)__float_as_uint(bestB) << 32) | (unsigned long long)((unsigned)iB + mbase);
    atomicMin(&keys[(size_t)bt * Nc + n0], kA);
    atomicMin(&keys[(size_t)bt * Nc + n1], kB);

    // ---- centroid partial sums (preds counted once: th==0; targets once: ph==0) ----
    float psx = blockSum(pAx + pBx, tid, sred);
    float psy = blockSum(pAy + pBy, tid, sred);
    float psz = blockSum(pAz + pBz, tid, sred);
    float tsx = blockSum(x0 + x1, tid, sred);
    float tsy = blockSum(y0 + y1, tid, sred);
    float tsz = blockSum(z0 + z1, tid, sred);
    if (tid == 0) {
        if (th == 0) {
            atomicAdd(&cent[bt * 6 + 0], psx);
            atomicAdd(&cent[bt * 6 + 1], psy);
            atomicAdd(&cent[bt * 6 + 2], psz);
        }
        if (ph == 0) {
            atomicAdd(&cent[bt * 6 + 3], tsx);
            atomicAdd(&cent[bt * 6 + 4], tsy);
            atomicAdd(&cent[bt * 6 + 5], tsz);
        }
    }
}

// Grid: 448 = 112 x 4 pred-quarters. Gather winning target, smooth-L1, reduce.
// Block 0 additionally finalizes the centroid loss (kernel-1 atomics are
// visible across the kernel boundary on the same stream).
__global__ __launch_bounds__(256) void finalize_kernel(
    const float* __restrict__ X, const float* __restrict__ Tg,
    const float* __restrict__ W,
    const unsigned long long* __restrict__ keys,
    const float* __restrict__ cent, float* __restrict__ out)
{
    __shared__ float sred[4];
    const int bt  = blockIdx.x >> 2;
    const int tid = threadIdx.x;
    const int n   = ((blockIdx.x & 3) << 8) | tid;

    const float* xb = X  + (size_t)bt * (Nc * Dc);
    const float* tb = Tg + (size_t)bt * (Nc * Dc);

    const unsigned idx = (unsigned)(keys[(size_t)bt * Nc + n] & 0xFFFFFFFFull);
    const float px = xb[n * 3 + 0], py = xb[n * 3 + 1], pz = xb[n * 3 + 2];
    const float tx = tb[idx * 3 + 0], ty = tb[idx * 3 + 1], tz = tb[idx * 3 + 2];
    float s = sl1(px - tx) + sl1(py - ty) + sl1(pz - tz);

    #pragma unroll
    for (int off = 32; off; off >>= 1) s += __shfl_down(s, off, 64);
    if ((tid & 63) == 0) sred[tid >> 6] = s;
    __syncthreads();
    if (tid == 0) {
        float tot = sred[0] + sred[1] + sred[2] + sred[3];
        // loss = sum_bt w_bt * (block sums / (N*D)) / B
        atomicAdd(out, tot * W[bt] * (1.0f / (Nc * Dc)) * (1.0f / Bc));
    }

    if (blockIdx.x == 0 && tid < BT) {
        const float* c = cent + tid * 6;
        const float inv = 1.0f / Nc;
        float l = sl1((c[0] - c[3]) * inv) + sl1((c[1] - c[4]) * inv) + sl1((c[2] - c[5]) * inv);
        atomicAdd(out + 1, l * (1.0f / (Bc * Dc)));  // lossc = sum / (B*3)
    }
}

extern "C" void kernel_launch(void* const* d_in, const int* in_sizes, int n_in,
                              void* d_out, int out_size, void* d_ws, size_t ws_size,
                              hipStream_t stream) {
    const float* X  = (const float*)d_in[0];  // X_v        [4,28,1024,3]
    const float* Tg = (const float*)d_in[1];  // target_X_v [4,28,1024,3]
    const float* W  = (const float*)d_in[2];  // weights    [4,28]
    float* out = (float*)d_out;               // {loss, lossc}

    // ws layout: [0, 112*1024*8) u64 argmin keys; then 112*6 floats centroid sums
    unsigned long long* keys = (unsigned long long*)d_ws;
    const size_t keys_bytes = (size_t)BT * Nc * sizeof(unsigned long long);  // 917504
    float* cent = (float*)((char*)d_ws + keys_bytes);

    hipMemsetAsync(out, 0, 2 * sizeof(float), stream);
    hipMemsetAsync(keys, 0xFF, keys_bytes, stream);          // u64 max -> atomicMin identity
    hipMemsetAsync(cent, 0, BT * 6 * sizeof(float), stream);

    chamfer_part_kernel<<<BT * 4, 256, 0, stream>>>(X, Tg, keys, cent);
    finalize_kernel<<<BT * 4, 256, 0, stream>>>(X, Tg, W, keys, cent, out);
}